// Round 1
// baseline (12244.543 us; speedup 1.0000x reference)
//
#include <hip/hip_runtime.h>
#include <math.h>

// Problem constants
#define NB 32      // batch
#define TE 128     // encoder length
#define NT 64      // decoder steps
#define HH 1024    // hidden
#define EE 512     // embed dim
#define VV 32000   // vocab
#define GG 4096    // 4*H

__device__ __forceinline__ float tanh_fast(float x) {
  float e = __expf(2.f * x);
  return 1.f - 2.f / (e + 1.f);   // safe at +/-inf
}
__device__ __forceinline__ float sigf(float x) { return 1.f / (1.f + __expf(-x)); }

// h_cur <- encoder_hidden[0], c_cur <- encoder_cell[0]
__global__ void k_init(const float* __restrict__ eh, const float* __restrict__ ec,
                       float* __restrict__ h_cur, float* __restrict__ c_cur) {
  int i = blockIdx.x * 256 + threadIdx.x;  // 32768
  h_cur[i] = eh[i];
  c_cur[i] = ec[i];
}

// emb_all[t*NB+b][e] = emb_table[tok(t,b)][e], padding_idx=0 -> 0, tok(0,b)=SOS=1
__global__ void k_emb(const int* __restrict__ tgt, const float* __restrict__ etab,
                      float* __restrict__ emb_all) {
  int idx = blockIdx.x * 256 + threadIdx.x;  // NT*NB*EE = 1048576
  int e = idx & (EE - 1);
  int tb = idx >> 9;
  int b = tb & (NB - 1);
  int t = tb >> 5;
  int tok = (t == 0) ? 1 : tgt[b * NT + (t - 1)];
  emb_all[idx] = (tok == 0) ? 0.f : etab[(size_t)tok * EE + e];
}

// dst[k][dst_j_off + j] = src[j][src_col_off + k]   (tiled transpose)
__global__ __launch_bounds__(256) void k_transpose(const float* __restrict__ src,
    int src_ld, int src_col_off, float* __restrict__ dst, int dst_ld, int dst_j_off) {
  __shared__ float tile[32][33];
  int j0 = blockIdx.x * 32, k0 = blockIdx.y * 32;
  int tj = threadIdx.x & 31, tk = threadIdx.x >> 5;  // 32 x 8
  for (int r = 0; r < 32; r += 8)
    tile[tk + r][tj] = src[(size_t)(j0 + tk + r) * src_ld + src_col_off + k0 + tj];
  __syncthreads();
  for (int r = 0; r < 32; r += 8)
    dst[(size_t)(k0 + tk + r) * dst_ld + dst_j_off + j0 + tj] = tile[tj][tk + r];
}

// C[m][n] = sum_k A[m][k]*W[n][k] (+ b1[n] + b2[n]); perm: out row = (m%32)*64 + m/32
// Tile 64x64, K-chunk 32, 256 threads, 4x4 accum per thread.
__global__ __launch_bounds__(256) void k_gemm_atb(
    const float* __restrict__ A, int lda,
    const float* __restrict__ W, int ldw,
    const float* __restrict__ b1, const float* __restrict__ b2,
    float* __restrict__ C, int ldc, int M, int N, int K, int perm) {
  __shared__ float As[32][64];  // [k][m]
  __shared__ float Ws[32][64];  // [k][n]
  const int m0 = blockIdx.y * 64, n0 = blockIdx.x * 64;
  const int tid = threadIdx.x;
  const int tn = (tid & 15) * 4;   // n within tile (lane-contiguous)
  const int tm = (tid >> 4) * 4;   // m within tile
  float acc[4][4] = {};
  for (int k0 = 0; k0 < K; k0 += 32) {
    for (int i = tid; i < 512; i += 256) {
      int row = i >> 3, kq = i & 7;
      float4 v = *(const float4*)(A + (size_t)(m0 + row) * lda + k0 + kq * 4);
      As[kq * 4 + 0][row] = v.x; As[kq * 4 + 1][row] = v.y;
      As[kq * 4 + 2][row] = v.z; As[kq * 4 + 3][row] = v.w;
    }
    for (int i = tid; i < 512; i += 256) {
      int row = i >> 3, kq = i & 7;
      float4 v = *(const float4*)(W + (size_t)(n0 + row) * ldw + k0 + kq * 4);
      Ws[kq * 4 + 0][row] = v.x; Ws[kq * 4 + 1][row] = v.y;
      Ws[kq * 4 + 2][row] = v.z; Ws[kq * 4 + 3][row] = v.w;
    }
    __syncthreads();
#pragma unroll 8
    for (int k = 0; k < 32; ++k) {
      float4 a4 = *(const float4*)&As[k][tm];
      float4 w4 = *(const float4*)&Ws[k][tn];
      const float aa[4] = {a4.x, a4.y, a4.z, a4.w};
      const float ww[4] = {w4.x, w4.y, w4.z, w4.w};
#pragma unroll
      for (int i = 0; i < 4; ++i)
#pragma unroll
        for (int j = 0; j < 4; ++j) acc[i][j] += aa[i] * ww[j];
    }
    __syncthreads();
  }
  float bias[4] = {0.f, 0.f, 0.f, 0.f};
  if (b1) {
#pragma unroll
    for (int j = 0; j < 4; ++j) bias[j] = b1[n0 + tn + j];
  }
  if (b2) {
#pragma unroll
    for (int j = 0; j < 4; ++j) bias[j] += b2[n0 + tn + j];
  }
#pragma unroll
  for (int i = 0; i < 4; ++i) {
    int m = m0 + tm + i;
    size_t row = perm ? ((size_t)(m & 31) * 64 + (m >> 5)) : (size_t)m;
    float4 v = make_float4(acc[i][0] + bias[0], acc[i][1] + bias[1],
                           acc[i][2] + bias[2], acc[i][3] + bias[3]);
    *(float4*)(C + row * ldc + n0 + tn) = v;
  }
}

// Small-M (M=32) GEMM with K-split partials: outP[ks][b][j] = sum_{k in chunk} x[b][k]*Wt[k][j]
// x: [32][1024], Wt: [1024][N]. grid = (N/64, K/kc). 256 threads.
__global__ __launch_bounds__(256) void k_smallgemm(const float* __restrict__ x,
    const float* __restrict__ Wt, float* __restrict__ outP, int N, int kc) {
  __shared__ float xs[32][64];
  const int j = blockIdx.x * 64 + (threadIdx.x & 63);
  const int bg = threadIdx.x >> 6;  // 0..3 -> 8 b's each
  const int kbase = blockIdx.y * kc;
  float acc[8] = {};
  for (int kb = 0; kb < kc; kb += 64) {
    for (int i = threadIdx.x; i < 512; i += 256) {
      int row = i >> 4, kq = i & 15;
      float4 v = *(const float4*)(x + (size_t)row * HH + kbase + kb + kq * 4);
      xs[row][kq * 4 + 0] = v.x; xs[row][kq * 4 + 1] = v.y;
      xs[row][kq * 4 + 2] = v.z; xs[row][kq * 4 + 3] = v.w;
    }
    __syncthreads();
    const float* wp = Wt + (size_t)(kbase + kb) * N + j;
#pragma unroll 8
    for (int k = 0; k < 64; ++k) {
      float w = wp[(size_t)k * N];
#pragma unroll
      for (int r = 0; r < 8; ++r) acc[r] += xs[bg * 8 + r][k] * w;
    }
    __syncthreads();
  }
#pragma unroll
  for (int r = 0; r < 8; ++r)
    outP[((size_t)blockIdx.y * 32 + bg * 8 + r) * N + j] = acc[r];
}

// Attention for one b per block (1024 threads): q = sum of 4 hW partials (j<1024),
// scores[t] = sum_h tanh(q[h]+encU[b][t][h])*Va[h]  (Va_b dropped: softmax-invariant),
// softmax over t, ctx[b][h] = sum_t w[t]*enc[b][t][h].
__global__ __launch_bounds__(1024) void k_attn(const float* __restrict__ hWp,
    const float* __restrict__ encU, const float* __restrict__ enc,
    const float* __restrict__ Va, float* __restrict__ ctx) {
  const int b = blockIdx.x;
  const int tid = threadIdx.x;
  __shared__ float qs[1024], vs[1024], sc[128], wt[128], red[128];
  {
    float q = 0.f;
#pragma unroll
    for (int s = 0; s < 4; ++s) q += hWp[((size_t)(s * 32 + b)) * 5120 + tid];
    qs[tid] = q;
    vs[tid] = Va[tid];
  }
  __syncthreads();
  const int wid = tid >> 6, lane = tid & 63;
  for (int it = 0; it < 8; ++it) {
    int t = wid * 8 + it;
    float a = 0.f;
    const float* ep = encU + ((size_t)(b * TE + t)) * HH;
#pragma unroll
    for (int c = 0; c < 4; ++c) {
      int i = c * 256 + lane * 4;
      float4 e = *(const float4*)(ep + i);
      float4 q4 = *(const float4*)(qs + i);
      float4 v4 = *(const float4*)(vs + i);
      a += tanh_fast(q4.x + e.x) * v4.x;
      a += tanh_fast(q4.y + e.y) * v4.y;
      a += tanh_fast(q4.z + e.z) * v4.z;
      a += tanh_fast(q4.w + e.w) * v4.w;
    }
#pragma unroll
    for (int s = 32; s > 0; s >>= 1) a += __shfl_xor(a, s);
    if (lane == 0) sc[t] = a;
  }
  __syncthreads();
  if (tid < 128) red[tid] = sc[tid];
  __syncthreads();
  for (int s = 64; s > 0; s >>= 1) {
    if (tid < s) red[tid] = fmaxf(red[tid], red[tid + s]);
    __syncthreads();
  }
  float mx = red[0];
  __syncthreads();
  if (tid < 128) {
    float e = __expf(sc[tid] - mx);
    red[tid] = e;
    wt[tid] = e;
  }
  __syncthreads();
  for (int s = 64; s > 0; s >>= 1) {
    if (tid < s) red[tid] += red[tid + s];
    __syncthreads();
  }
  float inv = 1.f / red[0];
  float a = 0.f;
  const float* e2 = enc + ((size_t)b * TE) * HH + tid;
  for (int t = 0; t < TE; ++t) a += wt[t] * e2[(size_t)t * HH];
  ctx[b * HH + tid] = a * inv;
}

// LSTM pointwise: gates = embG[t] + sum(gateP 8 partials) + sum(hWp Whh part 4 partials)
__global__ void k_lstm_pw(const float* __restrict__ gateP, const float* __restrict__ hWp,
    const float* __restrict__ embG, float* __restrict__ h_cur, float* __restrict__ c_cur,
    float* __restrict__ h_all, int t) {
  int idx = blockIdx.x * 256 + threadIdx.x;  // 32768
  int b = idx >> 10, jq = idx & 1023;
  float g4[4];
#pragma unroll
  for (int g = 0; g < 4; ++g) {
    float a = embG[((size_t)(t * NB + b)) * GG + g * 1024 + jq];
#pragma unroll
    for (int s = 0; s < 8; ++s) a += gateP[((size_t)(s * 32 + b)) * GG + g * 1024 + jq];
#pragma unroll
    for (int s = 0; s < 4; ++s) a += hWp[((size_t)(s * 32 + b)) * 5120 + 1024 + g * 1024 + jq];
    g4[g] = a;
  }
  float c = c_cur[idx];
  float iv = sigf(g4[0]), fv = sigf(g4[1]), gv = tanh_fast(g4[2]), ov = sigf(g4[3]);
  float cn = fv * c + iv * gv;
  float hn = ov * tanh_fast(cn);
  c_cur[idx] = cn;
  h_cur[idx] = hn;
  h_all[(size_t)t * (NB * HH) + idx] = hn;
}

// Row-wise in-place log-softmax over V (one block per output row)
__global__ __launch_bounds__(256) void k_logsoftmax(float* __restrict__ out) {
  const size_t row = blockIdx.x;
  float* p = out + row * VV;
  __shared__ float sm[256], ss[256];
  const int tid = threadIdx.x;
  float m = -1e30f, s = 0.f;
  for (int i = tid; i < VV; i += 256) {
    float x = p[i];
    float nm = fmaxf(m, x);
    s = s * __expf(m - nm) + __expf(x - nm);
    m = nm;
  }
  sm[tid] = m; ss[tid] = s;
  __syncthreads();
  for (int st = 128; st > 0; st >>= 1) {
    if (tid < st) {
      float m2 = fmaxf(sm[tid], sm[tid + st]);
      ss[tid] = ss[tid] * __expf(sm[tid] - m2) + ss[tid + st] * __expf(sm[tid + st] - m2);
      sm[tid] = m2;
    }
    __syncthreads();
  }
  float L = sm[0] + logf(ss[0]);
  __syncthreads();
  for (int i = tid; i < VV; i += 256) p[i] -= L;
}

extern "C" void kernel_launch(void* const* d_in, const int* in_sizes, int n_in,
                              void* d_out, int out_size, void* d_ws, size_t ws_size,
                              hipStream_t stream) {
  const float* enc   = (const float*)d_in[0];   // [32][128][1024]
  const float* ehid  = (const float*)d_in[1];   // [1][32][1024]
  const float* ecell = (const float*)d_in[2];
  const int*   tgt   = (const int*)d_in[3];     // [32][64]
  const float* etab  = (const float*)d_in[4];   // [32000][512]
  const float* Wa    = (const float*)d_in[5];   // [1024][1024]
  const float* Ua    = (const float*)d_in[6];
  const float* Va_w  = (const float*)d_in[7];   // [1][1024]
  // d_in[8] = Va_b: softmax-invariant constant, dropped
  const float* W_ih  = (const float*)d_in[9];   // [4096][1536]
  const float* W_hh  = (const float*)d_in[10];  // [4096][1024]
  const float* b_ih  = (const float*)d_in[11];
  const float* b_hh  = (const float*)d_in[12];
  const float* fc_w  = (const float*)d_in[13];  // [32000][1024]
  const float* fc_b  = (const float*)d_in[14];
  float* out = (float*)d_out;                   // [32][64][32000]
  float* ws = (float*)d_ws;

  // workspace layout (floats); total ~27.0M floats ~ 108 MB
  float* encU    = ws;                   // [32*128][1024] = 4194304
  float* emb_all = encU + 4194304;       // [64*32][512]   = 1048576
  float* embG    = emb_all + 1048576;    // [64*32][4096]  = 8388608
  float* WqhT    = embG + 8388608;       // [1024][5120]   = 5242880  ([Wa;W_hh]^T)
  float* WihcT   = WqhT + 5242880;       // [1024][4096]   = 4194304  (W_ih[:,512:]^T)
  float* h_all   = WihcT + 4194304;      // [64][32][1024] = 2097152
  float* h_cur   = h_all + 2097152;      // 32768
  float* c_cur   = h_cur + 32768;        // 32768
  float* hWp     = c_cur + 32768;        // [4][32][5120]  = 655360
  float* gateP   = hWp + 655360;         // [8][32][4096]  = 1048576
  float* ctx     = gateP + 1048576;      // 32768

  k_init<<<128, 256, 0, stream>>>(ehid, ecell, h_cur, c_cur);
  k_emb<<<4096, 256, 0, stream>>>(tgt, etab, emb_all);
  k_transpose<<<dim3(32, 32), 256, 0, stream>>>(Wa, 1024, 0, WqhT, 5120, 0);
  k_transpose<<<dim3(128, 32), 256, 0, stream>>>(W_hh, 1024, 0, WqhT, 5120, 1024);
  k_transpose<<<dim3(128, 32), 256, 0, stream>>>(W_ih, 1536, 512, WihcT, 4096, 0);
  // encU = enc @ Ua^T : M=4096, N=1024, K=1024
  k_gemm_atb<<<dim3(16, 64), 256, 0, stream>>>(enc, 1024, Ua, 1024, nullptr, nullptr,
                                               encU, 1024, 4096, 1024, 1024, 0);
  // embG = emb_all @ W_ih[:, :512]^T + b_ih + b_hh : M=2048, N=4096, K=512
  k_gemm_atb<<<dim3(64, 32), 256, 0, stream>>>(emb_all, 512, W_ih, 1536, b_ih, b_hh,
                                               embG, 4096, 2048, 4096, 512, 0);
  for (int t = 0; t < NT; ++t) {
    // hW = h @ [Wa;W_hh]^T : N=5120, K=1024, ksplit 4 (kc=256)
    k_smallgemm<<<dim3(80, 4), 256, 0, stream>>>(h_cur, WqhT, hWp, 5120, 256);
    k_attn<<<32, 1024, 0, stream>>>(hWp, encU, enc, Va_w, ctx);
    // gates(ctx part) : N=4096, K=1024, ksplit 8 (kc=128)
    k_smallgemm<<<dim3(64, 8), 256, 0, stream>>>(ctx, WihcT, gateP, 4096, 128);
    k_lstm_pw<<<128, 256, 0, stream>>>(gateP, hWp, embG, h_cur, c_cur, h_all, t);
  }
  // logits = h_all @ fc_w^T + fc_b, written with (b,t) permutation: M=2048, N=32000, K=1024
  k_gemm_atb<<<dim3(500, 32), 256, 0, stream>>>(h_all, 1024, fc_w, 1024, fc_b, nullptr,
                                                out, VV, 2048, VV, 1024, 1);
  k_logsoftmax<<<2048, 256, 0, stream>>>(out);
}

// Round 2
// 9799.020 us; speedup vs baseline: 1.2496x; 1.2496x over previous
//
#include <hip/hip_runtime.h>
#include <math.h>

// Problem constants
#define NB 32      // batch
#define TE 128     // encoder length
#define NT 64      // decoder steps
#define HH 1024    // hidden
#define EE 512     // embed dim
#define VV 32000   // vocab
#define GG 4096    // 4*H

typedef __attribute__((ext_vector_type(8))) short bh8;   // 8 bf16 (4 VGPRs)
typedef __attribute__((ext_vector_type(4))) float fx4;   // MFMA accumulator

__device__ __forceinline__ float tanh_fast(float x) {
  float e = __expf(2.f * x);
  return 1.f - 2.f / (e + 1.f);   // safe at +/-inf
}
__device__ __forceinline__ float sigf(float x) { return 1.f / (1.f + __expf(-x)); }
__device__ __forceinline__ ushort f2bf(float x) {  // RNE fp32 -> bf16 bits
  union { float f; unsigned u; } v; v.f = x;
  unsigned r = v.u + 0x7fffu + ((v.u >> 16) & 1u);
  return (ushort)(r >> 16);
}

// h_cur <- encoder_hidden[0], c_cur <- encoder_cell[0]
__global__ void k_init(const float* __restrict__ eh, const float* __restrict__ ec,
                       float* __restrict__ h_cur, float* __restrict__ c_cur) {
  int i = blockIdx.x * 256 + threadIdx.x;  // 32768
  h_cur[i] = eh[i];
  c_cur[i] = ec[i];
}

// emb_bf[t*NB+b][e] = bf16(emb_table[tok(t,b)][e]), padding_idx=0 -> 0, tok(0,b)=SOS=1
__global__ void k_emb(const int* __restrict__ tgt, const float* __restrict__ etab,
                      ushort* __restrict__ emb_bf) {
  int idx = blockIdx.x * 256 + threadIdx.x;  // NT*NB*EE = 1048576
  int e = idx & (EE - 1);
  int tb = idx >> 9;
  int b = tb & (NB - 1);
  int t = tb >> 5;
  int tok = (t == 0) ? 1 : tgt[b * NT + (t - 1)];
  emb_bf[idx] = (tok == 0) ? (ushort)0 : f2bf(etab[(size_t)tok * EE + e]);
}

// fp32 -> bf16 (n4 = count/4)
__global__ void k_f2b(const float* __restrict__ s, ushort* __restrict__ d, int n4) {
  int i = blockIdx.x * 256 + threadIdx.x;
  if (i >= n4) return;
  float4 v = *(const float4*)(s + (size_t)i * 4);
  *(ushort4*)(d + (size_t)i * 4) = make_ushort4(f2bf(v.x), f2bf(v.y), f2bf(v.z), f2bf(v.w));
}

// W_ih[:, :512] (ld 1536) -> contiguous bf16 [4096][512]
__global__ void k_f2b_wih(const float* __restrict__ s, ushort* __restrict__ d) {
  int i = blockIdx.x * 256 + threadIdx.x;  // 524288
  int r = i >> 7, c = (i & 127) * 4;
  float4 v = *(const float4*)(s + (size_t)r * 1536 + c);
  *(ushort4*)(d + (size_t)r * 512 + c) = make_ushort4(f2bf(v.x), f2bf(v.y), f2bf(v.z), f2bf(v.w));
}

// dst[k][dst_j_off + j] = src[j][src_col_off + k]   (tiled transpose, fp32)
__global__ __launch_bounds__(256) void k_transpose(const float* __restrict__ src,
    int src_ld, int src_col_off, float* __restrict__ dst, int dst_ld, int dst_j_off) {
  __shared__ float tile[32][33];
  int j0 = blockIdx.x * 32, k0 = blockIdx.y * 32;
  int tj = threadIdx.x & 31, tk = threadIdx.x >> 5;  // 32 x 8
  for (int r = 0; r < 32; r += 8)
    tile[tk + r][tj] = src[(size_t)(j0 + tk + r) * src_ld + src_col_off + k0 + tj];
  __syncthreads();
  for (int r = 0; r < 32; r += 8)
    dst[(size_t)(k0 + tk + r) * dst_ld + dst_j_off + j0 + tj] = tile[tj][tk + r];
}

// ---- bf16 MFMA GEMM, m97 structure: 128x128 tile, BK=32, 4 waves 2x2,
// C[m][n] = sum_k A[m][k]*B[n][k] (+b1[n]+b2[n]); perm: out row = (m%32)*64 + m/32
__device__ __forceinline__ void stage_pair(const ushort* A, int lda, const ushort* B, int ldb,
    int m0, int n0, int k0, ushort* ldsA, ushort* ldsB, int tid) {
  const int w = tid >> 6;
  const int row = tid >> 2;          // rows 0..63 (chunk 0), +64 (chunk 1)
  const int kq = (tid & 3) * 8;      // 8 bf16 = 16 B per lane
  const ushort* ga = A + (size_t)(m0 + row) * lda + k0 + kq;
  const ushort* gb = B + (size_t)(n0 + row) * ldb + k0 + kq;
  ushort* la = ldsA + w * 512;       // wave-uniform base; HW adds lane*16B
  ushort* lb = ldsB + w * 512;
  __builtin_amdgcn_global_load_lds((const __attribute__((address_space(1))) void*)ga,
      (__attribute__((address_space(3))) void*)la, 16, 0, 0);
  __builtin_amdgcn_global_load_lds((const __attribute__((address_space(1))) void*)(ga + (size_t)64 * lda),
      (__attribute__((address_space(3))) void*)(la + 2048), 16, 0, 0);
  __builtin_amdgcn_global_load_lds((const __attribute__((address_space(1))) void*)gb,
      (__attribute__((address_space(3))) void*)lb, 16, 0, 0);
  __builtin_amdgcn_global_load_lds((const __attribute__((address_space(1))) void*)(gb + (size_t)64 * ldb),
      (__attribute__((address_space(3))) void*)(lb + 2048), 16, 0, 0);
}

__global__ __launch_bounds__(256) void k_gemm_bf16(
    const ushort* __restrict__ A, int lda,
    const ushort* __restrict__ B, int ldb,
    const float* __restrict__ b1, const float* __restrict__ b2,
    float* __restrict__ C, int ldc, int K, int perm) {
  __shared__ ushort lds[2][2][4096];   // [buf][A/B][row*32+k], 32 KB
  const int tid = threadIdx.x;
  const int lane = tid & 63, w = tid >> 6;
  const int m0 = blockIdx.y * 128, n0 = blockIdx.x * 128;
  const int wm = (w >> 1) * 64, wn = (w & 1) * 64;
  fx4 acc[4][4] = {};
  stage_pair(A, lda, B, ldb, m0, n0, 0, lds[0][0], lds[0][1], tid);
  __syncthreads();
  const int nk = K >> 5;
  const int ko = (lane >> 4) * 8;        // frag k-offset
  const int rA = wm + (lane & 15);
  const int rB = wn + (lane & 15);
  for (int ks = 0; ks < nk; ++ks) {
    const int cur = ks & 1;
    if (ks + 1 < nk)
      stage_pair(A, lda, B, ldb, m0, n0, (ks + 1) << 5, lds[cur ^ 1][0], lds[cur ^ 1][1], tid);
    bh8 af[4], bfr[4];
#pragma unroll
    for (int f = 0; f < 4; ++f) {
      af[f]  = *(const bh8*)(&lds[cur][0][(rA + f * 16) * 32 + ko]);
      bfr[f] = *(const bh8*)(&lds[cur][1][(rB + f * 16) * 32 + ko]);
    }
#pragma unroll
    for (int i = 0; i < 4; ++i)
#pragma unroll
      for (int j = 0; j < 4; ++j)
        acc[i][j] = __builtin_amdgcn_mfma_f32_16x16x32_bf16(af[i], bfr[j], acc[i][j], 0, 0, 0);
    __syncthreads();
  }
#pragma unroll
  for (int j = 0; j < 4; ++j) {
    const int col = n0 + wn + j * 16 + (lane & 15);
    const float bv = (b1 ? b1[col] : 0.f) + (b2 ? b2[col] : 0.f);
#pragma unroll
    for (int i = 0; i < 4; ++i) {
      const int mb = m0 + wm + i * 16 + (lane >> 4) * 4;
#pragma unroll
      for (int r = 0; r < 4; ++r) {
        const int m = mb + r;
        const size_t orow = perm ? ((size_t)(m & 31) * 64 + (m >> 5)) : (size_t)m;
        C[orow * (size_t)ldc + col] = acc[i][j][r] + bv;
      }
    }
  }
}

// Small-M (M=32) GEMM with K-split partials: outP[ks][b][j] = sum_{k in chunk} x[b][k]*Wt[k][j]
__global__ __launch_bounds__(256) void k_smallgemm(const float* __restrict__ x,
    const float* __restrict__ Wt, float* __restrict__ outP, int N, int kc) {
  __shared__ float xs[32][64];
  const int j = blockIdx.x * 64 + (threadIdx.x & 63);
  const int bg = threadIdx.x >> 6;  // 0..3 -> 8 b's each
  const int kbase = blockIdx.y * kc;
  float acc[8] = {};
  for (int kb = 0; kb < kc; kb += 64) {
    for (int i = threadIdx.x; i < 512; i += 256) {
      int row = i >> 4, kq = i & 15;
      float4 v = *(const float4*)(x + (size_t)row * HH + kbase + kb + kq * 4);
      xs[row][kq * 4 + 0] = v.x; xs[row][kq * 4 + 1] = v.y;
      xs[row][kq * 4 + 2] = v.z; xs[row][kq * 4 + 3] = v.w;
    }
    __syncthreads();
    const float* wp = Wt + (size_t)(kbase + kb) * N + j;
#pragma unroll 8
    for (int k = 0; k < 64; ++k) {
      float w = wp[(size_t)k * N];
#pragma unroll
      for (int r = 0; r < 8; ++r) acc[r] += xs[bg * 8 + r][k] * w;
    }
    __syncthreads();
  }
#pragma unroll
  for (int r = 0; r < 8; ++r)
    outP[((size_t)blockIdx.y * 32 + bg * 8 + r) * N + j] = acc[r];
}

// Attention for one b per block (1024 threads)
__global__ __launch_bounds__(1024) void k_attn(const float* __restrict__ hWp,
    const float* __restrict__ encU, const float* __restrict__ enc,
    const float* __restrict__ Va, float* __restrict__ ctx) {
  const int b = blockIdx.x;
  const int tid = threadIdx.x;
  __shared__ float qs[1024], vs[1024], sc[128], wt[128], red[128];
  {
    float q = 0.f;
#pragma unroll
    for (int s = 0; s < 4; ++s) q += hWp[((size_t)(s * 32 + b)) * 5120 + tid];
    qs[tid] = q;
    vs[tid] = Va[tid];
  }
  __syncthreads();
  const int wid = tid >> 6, lane = tid & 63;
  for (int it = 0; it < 8; ++it) {
    int t = wid * 8 + it;
    float a = 0.f;
    const float* ep = encU + ((size_t)(b * TE + t)) * HH;
#pragma unroll
    for (int c = 0; c < 4; ++c) {
      int i = c * 256 + lane * 4;
      float4 e = *(const float4*)(ep + i);
      float4 q4 = *(const float4*)(qs + i);
      float4 v4 = *(const float4*)(vs + i);
      a += tanh_fast(q4.x + e.x) * v4.x;
      a += tanh_fast(q4.y + e.y) * v4.y;
      a += tanh_fast(q4.z + e.z) * v4.z;
      a += tanh_fast(q4.w + e.w) * v4.w;
    }
#pragma unroll
    for (int s = 32; s > 0; s >>= 1) a += __shfl_xor(a, s);
    if (lane == 0) sc[t] = a;
  }
  __syncthreads();
  if (tid < 128) red[tid] = sc[tid];
  __syncthreads();
  for (int s = 64; s > 0; s >>= 1) {
    if (tid < s) red[tid] = fmaxf(red[tid], red[tid + s]);
    __syncthreads();
  }
  float mx = red[0];
  __syncthreads();
  if (tid < 128) {
    float e = __expf(sc[tid] - mx);
    red[tid] = e;
    wt[tid] = e;
  }
  __syncthreads();
  for (int s = 64; s > 0; s >>= 1) {
    if (tid < s) red[tid] += red[tid + s];
    __syncthreads();
  }
  float inv = 1.f / red[0];
  float a = 0.f;
  const float* e2 = enc + ((size_t)b * TE) * HH + tid;
  for (int t = 0; t < TE; ++t) a += wt[t] * e2[(size_t)t * HH];
  ctx[b * HH + tid] = a * inv;
}

// LSTM pointwise; writes h_cur (fp32) and hall_bf (bf16 row t*NB+b)
__global__ void k_lstm_pw(const float* __restrict__ gateP, const float* __restrict__ hWp,
    const float* __restrict__ embG, float* __restrict__ h_cur, float* __restrict__ c_cur,
    ushort* __restrict__ hall_bf, int t) {
  int idx = blockIdx.x * 256 + threadIdx.x;  // 32768
  int b = idx >> 10, jq = idx & 1023;
  float g4[4];
#pragma unroll
  for (int g = 0; g < 4; ++g) {
    float a = embG[((size_t)(t * NB + b)) * GG + g * 1024 + jq];
#pragma unroll
    for (int s = 0; s < 8; ++s) a += gateP[((size_t)(s * 32 + b)) * GG + g * 1024 + jq];
#pragma unroll
    for (int s = 0; s < 4; ++s) a += hWp[((size_t)(s * 32 + b)) * 5120 + 1024 + g * 1024 + jq];
    g4[g] = a;
  }
  float c = c_cur[idx];
  float iv = sigf(g4[0]), fv = sigf(g4[1]), gv = tanh_fast(g4[2]), ov = sigf(g4[3]);
  float cn = fv * c + iv * gv;
  float hn = ov * tanh_fast(cn);
  c_cur[idx] = cn;
  h_cur[idx] = hn;
  hall_bf[(size_t)t * (NB * HH) + idx] = f2bf(hn);
}

// Row-wise in-place log-softmax over V (one block per output row)
__global__ __launch_bounds__(256) void k_logsoftmax(float* __restrict__ out) {
  const size_t row = blockIdx.x;
  float* p = out + row * VV;
  __shared__ float sm[256], ss[256];
  const int tid = threadIdx.x;
  float m = -1e30f, s = 0.f;
  for (int i = tid; i < VV; i += 256) {
    float x = p[i];
    float nm = fmaxf(m, x);
    s = s * __expf(m - nm) + __expf(x - nm);
    m = nm;
  }
  sm[tid] = m; ss[tid] = s;
  __syncthreads();
  for (int st = 128; st > 0; st >>= 1) {
    if (tid < st) {
      float m2 = fmaxf(sm[tid], sm[tid + st]);
      ss[tid] = ss[tid] * __expf(sm[tid] - m2) + ss[tid + st] * __expf(sm[tid + st] - m2);
      sm[tid] = m2;
    }
    __syncthreads();
  }
  float L = sm[0] + logf(ss[0]);
  __syncthreads();
  for (int i = tid; i < VV; i += 256) p[i] -= L;
}

extern "C" void kernel_launch(void* const* d_in, const int* in_sizes, int n_in,
                              void* d_out, int out_size, void* d_ws, size_t ws_size,
                              hipStream_t stream) {
  const float* enc   = (const float*)d_in[0];   // [32][128][1024]
  const float* ehid  = (const float*)d_in[1];   // [1][32][1024]
  const float* ecell = (const float*)d_in[2];
  const int*   tgt   = (const int*)d_in[3];     // [32][64]
  const float* etab  = (const float*)d_in[4];   // [32000][512]
  const float* Wa    = (const float*)d_in[5];   // [1024][1024]
  const float* Ua    = (const float*)d_in[6];
  const float* Va_w  = (const float*)d_in[7];   // [1][1024]
  // d_in[8] = Va_b: softmax-invariant constant, dropped
  const float* W_ih  = (const float*)d_in[9];   // [4096][1536]
  const float* W_hh  = (const float*)d_in[10];  // [4096][1024]
  const float* b_ih  = (const float*)d_in[11];
  const float* b_hh  = (const float*)d_in[12];
  const float* fc_w  = (const float*)d_in[13];  // [32000][1024]
  const float* fc_b  = (const float*)d_in[14];
  float* out = (float*)d_out;                   // [32][64][32000] (b-major)
  float* ws = (float*)d_ws;

  // workspace (floats), ~116 MB total
  float* encU  = ws;                 // 4,194,304
  float* embG  = ws + 4194304;       // 8,388,608
  float* WqhT  = ws + 12582912;      // 5,242,880   [Wa;W_hh]^T fp32
  float* WihcT = ws + 17825792;      // 4,194,304   W_ih[:,512:]^T fp32
  float* h_cur = ws + 22020096;      // 32,768
  float* c_cur = ws + 22052864;      // 32,768
  float* hWp   = ws + 22085632;      // 655,360  [4][32][5120]
  float* gateP = ws + 22740992;      // 1,048,576 [8][32][4096]
  float* ctx   = ws + 23789568;      // 32,768
  ushort* enc_bf  = (ushort*)(ws + 23822336);  // [4096][1024]
  ushort* Ua_bf   = (ushort*)(ws + 25919488);  // [1024][1024]
  ushort* emb_bf  = (ushort*)(ws + 26443776);  // [2048][512]
  ushort* WihE_bf = (ushort*)(ws + 26968064);  // [4096][512]
  ushort* hall_bf = (ushort*)(ws + 28016640);  // [2048][1024]
  ushort* fcw_bf  = (ushort*)ws;     // [32000][1024] bf16 — reuses encU/embG AFTER recurrence

  k_init<<<128, 256, 0, stream>>>(ehid, ecell, h_cur, c_cur);
  k_emb<<<4096, 256, 0, stream>>>(tgt, etab, emb_bf);
  k_transpose<<<dim3(32, 32), 256, 0, stream>>>(Wa, 1024, 0, WqhT, 5120, 0);
  k_transpose<<<dim3(128, 32), 256, 0, stream>>>(W_hh, 1024, 0, WqhT, 5120, 1024);
  k_transpose<<<dim3(128, 32), 256, 0, stream>>>(W_ih, 1536, 512, WihcT, 4096, 0);
  k_f2b<<<4096, 256, 0, stream>>>(enc, enc_bf, 1048576);
  k_f2b<<<1024, 256, 0, stream>>>(Ua, Ua_bf, 262144);
  k_f2b_wih<<<2048, 256, 0, stream>>>(W_ih, WihE_bf);
  // encU = enc @ Ua^T : M=4096, N=1024, K=1024 (bf16 MFMA, fp32 out)
  k_gemm_bf16<<<dim3(8, 32), 256, 0, stream>>>(enc_bf, 1024, Ua_bf, 1024, nullptr, nullptr,
                                               encU, 1024, 1024, 0);
  // embG = emb @ W_ih[:,:512]^T + b_ih + b_hh : M=2048, N=4096, K=512
  k_gemm_bf16<<<dim3(32, 16), 256, 0, stream>>>(emb_bf, 512, WihE_bf, 512, b_ih, b_hh,
                                                embG, 4096, 512, 0);
  for (int t = 0; t < NT; ++t) {
    k_smallgemm<<<dim3(80, 4), 256, 0, stream>>>(h_cur, WqhT, hWp, 5120, 256);
    k_attn<<<32, 1024, 0, stream>>>(hWp, encU, enc, Va_w, ctx);
    k_smallgemm<<<dim3(64, 8), 256, 0, stream>>>(ctx, WihcT, gateP, 4096, 128);
    k_lstm_pw<<<128, 256, 0, stream>>>(gateP, hWp, embG, h_cur, c_cur, hall_bf, t);
  }
  // fc_w -> bf16 into the region encU/embG occupied (dead after recurrence)
  k_f2b<<<32000, 256, 0, stream>>>(fc_w, fcw_bf, 8192000);
  // logits = h_all @ fc_w^T + fc_b, perm store (b,t): M=2048, N=32000, K=1024
  k_gemm_bf16<<<dim3(250, 16), 256, 0, stream>>>(hall_bf, 1024, fcw_bf, 1024, fc_b, nullptr,
                                                 out, VV, 1024, 1);
  k_logsoftmax<<<2048, 256, 0, stream>>>(out);
}

// Round 3
// 2695.520 us; speedup vs baseline: 4.5426x; 3.6353x over previous
//
#include <hip/hip_runtime.h>
#include <math.h>

// Problem constants
#define NB 32      // batch
#define TE 128     // encoder length
#define NT 64      // decoder steps
#define HH 1024    // hidden
#define EE 512     // embed dim
#define VV 32000   // vocab
#define GG 4096    // 4*H
#define WQN 5120   // Wa(1024) + W_hh(4096) output cols

typedef __attribute__((ext_vector_type(8))) short bh8;   // 8 bf16 (4 VGPRs)
typedef __attribute__((ext_vector_type(4))) float fx4;   // MFMA accumulator

__device__ __forceinline__ float tanh_fast(float x) {
  float e = __expf(2.f * x);
  return 1.f - 2.f / (e + 1.f);   // safe at +/-inf
}
__device__ __forceinline__ float sigf(float x) { return 1.f / (1.f + __expf(-x)); }
__device__ __forceinline__ ushort f2bf(float x) {  // RNE fp32 -> bf16 bits
  union { float f; unsigned u; } v; v.f = x;
  unsigned r = v.u + 0x7fffu + ((v.u >> 16) & 1u);
  return (ushort)(r >> 16);
}
__device__ __forceinline__ float bf2f(ushort u) {
  return __uint_as_float(((unsigned)u) << 16);
}

// h_bf <- bf16(encoder_hidden[0]), c_cur <- encoder_cell[0]
__global__ void k_init(const float* __restrict__ eh, const float* __restrict__ ec,
                       ushort* __restrict__ h_bf, float* __restrict__ c_cur) {
  int i = blockIdx.x * 256 + threadIdx.x;  // 32768
  h_bf[i] = f2bf(eh[i]);
  c_cur[i] = ec[i];
}

// emb_bf[t*NB+b][e] = bf16(emb_table[tok(t,b)][e]), padding_idx=0 -> 0, tok(0,b)=SOS=1
__global__ void k_emb(const int* __restrict__ tgt, const float* __restrict__ etab,
                      ushort* __restrict__ emb_bf) {
  int idx = blockIdx.x * 256 + threadIdx.x;  // NT*NB*EE = 1048576
  int e = idx & (EE - 1);
  int tb = idx >> 9;
  int b = tb & (NB - 1);
  int t = tb >> 5;
  int tok = (t == 0) ? 1 : tgt[b * NT + (t - 1)];
  emb_bf[idx] = (tok == 0) ? (ushort)0 : f2bf(etab[(size_t)tok * EE + e]);
}

// fp32 -> bf16, contiguous (n4 = count/4)
__global__ void k_f2b(const float* __restrict__ s, ushort* __restrict__ d, int n4) {
  int i = blockIdx.x * 256 + threadIdx.x;
  if (i >= n4) return;
  float4 v = *(const float4*)(s + (size_t)i * 4);
  *(ushort4*)(d + (size_t)i * 4) = make_ushort4(f2bf(v.x), f2bf(v.y), f2bf(v.z), f2bf(v.w));
}

// strided fp32 -> bf16: d[r][c] = bf16(s[r][off+c]), c < w4*4, dst ld = w4*4
__global__ void k_f2b_s(const float* __restrict__ s, int ld, int off, int w4,
                        ushort* __restrict__ d, int n) {
  int i = blockIdx.x * 256 + threadIdx.x;
  if (i >= n) return;
  int r = i / w4, c = (i - r * w4) * 4;
  float4 v = *(const float4*)(s + (size_t)r * ld + off + c);
  *(ushort4*)(d + (size_t)r * (w4 * 4) + c) = make_ushort4(f2bf(v.x), f2bf(v.y), f2bf(v.z), f2bf(v.w));
}

// ---- bf16 MFMA GEMM (m97 structure): 128x128 tile, BK=32, 4 waves 2x2.
// C[m][n] = sum_k A[m][k]*B[n][k] (+b1[n]+b2[n]); perm: out row = (m%32)*64 + m/32;
// obf: store bf16 instead of f32.
__device__ __forceinline__ void stage_pair(const ushort* A, int lda, const ushort* B, int ldb,
    int m0, int n0, int k0, ushort* ldsA, ushort* ldsB, int tid) {
  const int w = tid >> 6;
  const int row = tid >> 2;          // rows 0..63 (chunk 0), +64 (chunk 1)
  const int kq = (tid & 3) * 8;      // 8 bf16 = 16 B per lane
  const ushort* ga = A + (size_t)(m0 + row) * lda + k0 + kq;
  const ushort* gb = B + (size_t)(n0 + row) * ldb + k0 + kq;
  ushort* la = ldsA + w * 512;       // wave-uniform base; HW adds lane*16B
  ushort* lb = ldsB + w * 512;
  __builtin_amdgcn_global_load_lds((const __attribute__((address_space(1))) void*)ga,
      (__attribute__((address_space(3))) void*)la, 16, 0, 0);
  __builtin_amdgcn_global_load_lds((const __attribute__((address_space(1))) void*)(ga + (size_t)64 * lda),
      (__attribute__((address_space(3))) void*)(la + 2048), 16, 0, 0);
  __builtin_amdgcn_global_load_lds((const __attribute__((address_space(1))) void*)gb,
      (__attribute__((address_space(3))) void*)lb, 16, 0, 0);
  __builtin_amdgcn_global_load_lds((const __attribute__((address_space(1))) void*)(gb + (size_t)64 * ldb),
      (__attribute__((address_space(3))) void*)(lb + 2048), 16, 0, 0);
}

__global__ __launch_bounds__(256) void k_gemm_bf16(
    const ushort* __restrict__ A, int lda,
    const ushort* __restrict__ B, int ldb,
    const float* __restrict__ b1, const float* __restrict__ b2,
    void* __restrict__ Cv, int ldc, int K, int perm, int obf) {
  __shared__ ushort lds[2][2][4096];   // [buf][A/B][row*32+k], 32 KB
  const int tid = threadIdx.x;
  const int lane = tid & 63, w = tid >> 6;
  const int m0 = blockIdx.y * 128, n0 = blockIdx.x * 128;
  const int wm = (w >> 1) * 64, wn = (w & 1) * 64;
  fx4 acc[4][4] = {};
  stage_pair(A, lda, B, ldb, m0, n0, 0, lds[0][0], lds[0][1], tid);
  __syncthreads();
  const int nk = K >> 5;
  const int ko = (lane >> 4) * 8;        // frag k-offset
  const int rA = wm + (lane & 15);
  const int rB = wn + (lane & 15);
  for (int ks = 0; ks < nk; ++ks) {
    const int cur = ks & 1;
    if (ks + 1 < nk)
      stage_pair(A, lda, B, ldb, m0, n0, (ks + 1) << 5, lds[cur ^ 1][0], lds[cur ^ 1][1], tid);
    bh8 af[4], bfr[4];
#pragma unroll
    for (int f = 0; f < 4; ++f) {
      af[f]  = *(const bh8*)(&lds[cur][0][(rA + f * 16) * 32 + ko]);
      bfr[f] = *(const bh8*)(&lds[cur][1][(rB + f * 16) * 32 + ko]);
    }
#pragma unroll
    for (int i = 0; i < 4; ++i)
#pragma unroll
      for (int j = 0; j < 4; ++j)
        acc[i][j] = __builtin_amdgcn_mfma_f32_16x16x32_bf16(af[i], bfr[j], acc[i][j], 0, 0, 0);
    __syncthreads();
  }
  float* Cf = (float*)Cv;
  ushort* Cb = (ushort*)Cv;
#pragma unroll
  for (int j = 0; j < 4; ++j) {
    const int col = n0 + wn + j * 16 + (lane & 15);
    const float bv = (b1 ? b1[col] : 0.f) + (b2 ? b2[col] : 0.f);
#pragma unroll
    for (int i = 0; i < 4; ++i) {
      const int mb = m0 + wm + i * 16 + (lane >> 4) * 4;
#pragma unroll
      for (int r = 0; r < 4; ++r) {
        const int m = mb + r;
        const size_t orow = perm ? ((size_t)(m & 31) * 64 + (m >> 5)) : (size_t)m;
        const float v = acc[i][j][r] + bv;
        if (obf) Cb[orow * (size_t)ldc + col] = f2bf(v);
        else     Cf[orow * (size_t)ldc + col] = v;
      }
    }
  }
}

// K1: hWp[ks][b][n] = sum_{k in half ks} h_bf[b][k] * Wqh[n][k]
// grid (40, 2), 256 thr (4 waves); wave covers 32 n, M=32, direct-from-global MFMA.
__global__ __launch_bounds__(256) void k_hw(const ushort* __restrict__ h_bf,
    const ushort* __restrict__ Wqh, float* __restrict__ hWp) {
  const int tid = threadIdx.x, lane = tid & 63, w = tid >> 6;
  const int n_base = blockIdx.x * 128 + w * 32;
  const int kb = blockIdx.y * 512;
  const int r15 = lane & 15, ko = (lane >> 4) * 8;
  const ushort* A0 = h_bf + (size_t)r15 * HH + kb + ko;
  const ushort* A1 = A0 + 16 * HH;
  const ushort* B0 = Wqh + (size_t)(n_base + r15) * HH + kb + ko;
  const ushort* B1 = B0 + 16 * HH;
  fx4 a00 = {}, a01 = {}, a10 = {}, a11 = {};
#pragma unroll 4
  for (int ks = 0; ks < 16; ++ks) {
    const int k = ks * 32;
    bh8 av0 = *(const bh8*)(A0 + k), av1 = *(const bh8*)(A1 + k);
    bh8 bv0 = *(const bh8*)(B0 + k), bv1 = *(const bh8*)(B1 + k);
    a00 = __builtin_amdgcn_mfma_f32_16x16x32_bf16(av0, bv0, a00, 0, 0, 0);
    a01 = __builtin_amdgcn_mfma_f32_16x16x32_bf16(av0, bv1, a01, 0, 0, 0);
    a10 = __builtin_amdgcn_mfma_f32_16x16x32_bf16(av1, bv0, a10, 0, 0, 0);
    a11 = __builtin_amdgcn_mfma_f32_16x16x32_bf16(av1, bv1, a11, 0, 0, 0);
  }
  float* out = hWp + (size_t)blockIdx.y * (NB * WQN);
  const int rr = (lane >> 4) * 4;
#pragma unroll
  for (int r = 0; r < 4; ++r) {
    out[(size_t)(rr + r) * WQN + n_base + r15]           = a00[r];
    out[(size_t)(rr + r) * WQN + n_base + 16 + r15]      = a01[r];
    out[(size_t)(16 + rr + r) * WQN + n_base + r15]      = a10[r];
    out[(size_t)(16 + rr + r) * WQN + n_base + 16 + r15] = a11[r];
  }
}

// K2a: scores[b][t] = sum_h tanh(q[h] + encU_bf[b][t][h]) * Va[h]
// grid (8, 32): y=b, x=t-chunk of 16. 4 waves, wave handles 4 t's.
__global__ __launch_bounds__(256) void k_scores(const float* __restrict__ hWp,
    const ushort* __restrict__ encU, const float* __restrict__ Va,
    float* __restrict__ sc) {
  const int b = blockIdx.y, tc = blockIdx.x;
  const int tid = threadIdx.x, lane = tid & 63, w = tid >> 6;
  // q (cols 0..1023 of hW, sum of 2 K-partials) and Va into registers: 8 each per chunk
  float qr[16], vr[16];
#pragma unroll
  for (int c = 0; c < 2; ++c) {
    const int h0 = c * 512 + lane * 8;
    float4 p0a = *(const float4*)(hWp + (size_t)b * WQN + h0);
    float4 p0b = *(const float4*)(hWp + (size_t)b * WQN + h0 + 4);
    float4 p1a = *(const float4*)(hWp + (size_t)(NB * WQN) + (size_t)b * WQN + h0);
    float4 p1b = *(const float4*)(hWp + (size_t)(NB * WQN) + (size_t)b * WQN + h0 + 4);
    float4 va  = *(const float4*)(Va + h0);
    float4 vb  = *(const float4*)(Va + h0 + 4);
    qr[c*8+0] = p0a.x + p1a.x; qr[c*8+1] = p0a.y + p1a.y;
    qr[c*8+2] = p0a.z + p1a.z; qr[c*8+3] = p0a.w + p1a.w;
    qr[c*8+4] = p0b.x + p1b.x; qr[c*8+5] = p0b.y + p1b.y;
    qr[c*8+6] = p0b.z + p1b.z; qr[c*8+7] = p0b.w + p1b.w;
    vr[c*8+0] = va.x; vr[c*8+1] = va.y; vr[c*8+2] = va.z; vr[c*8+3] = va.w;
    vr[c*8+4] = vb.x; vr[c*8+5] = vb.y; vr[c*8+6] = vb.z; vr[c*8+7] = vb.w;
  }
#pragma unroll
  for (int it = 0; it < 4; ++it) {
    const int t = tc * 16 + w * 4 + it;
    const ushort* ep = encU + (size_t)(b * TE + t) * HH;
    float a = 0.f;
#pragma unroll
    for (int c = 0; c < 2; ++c) {
      bh8 e8 = *(const bh8*)(ep + c * 512 + lane * 8);
#pragma unroll
      for (int j = 0; j < 8; ++j) {
        float ef = bf2f((ushort)e8[j]);
        a += tanh_fast(qr[c*8+j] + ef) * vr[c*8+j];
      }
    }
#pragma unroll
    for (int s = 32; s > 0; s >>= 1) a += __shfl_xor(a, s);
    if (lane == 0) sc[b * TE + t] = a;
  }
}

// K2b: softmax(sc[b]) -> gates via weighted encW sum + embG + hW(Whh part) -> LSTM pointwise.
// grid (4, 32): y=b, x=h-quarter (256 units). 256 thr: wave = gate, lane covers 4 units.
__global__ __launch_bounds__(256) void k_ctxlstm(const float* __restrict__ sc,
    const ushort* __restrict__ encW, const float* __restrict__ hWp,
    const float* __restrict__ embG, float* __restrict__ c_cur,
    ushort* __restrict__ h_bf, ushort* __restrict__ hall, int t) {
  const int b = blockIdx.y, hq = blockIdx.x;
  const int tid = threadIdx.x, lane = tid & 63, g = tid >> 6;
  __shared__ float red[256], wt[128], gp[4][256];
  // softmax over 128 scores (unnormalized exp; defer 1/sum)
  float s = (tid < TE) ? sc[b * TE + tid] : -1e30f;
  red[tid] = s; __syncthreads();
  for (int st = 128; st > 0; st >>= 1) {
    if (tid < st) red[tid] = fmaxf(red[tid], red[tid + st]);
    __syncthreads();
  }
  const float mx = red[0];
  __syncthreads();
  float e = (tid < TE) ? __expf(s - mx) : 0.f;
  if (tid < TE) wt[tid] = e;
  red[tid] = e; __syncthreads();
  for (int st = 128; st > 0; st >>= 1) {
    if (tid < st) red[tid] += red[tid + st];
    __syncthreads();
  }
  const float inv = 1.f / red[0];
  // weighted sum of encW rows: thread handles gate g, units u4..u4+3
  const int u4 = hq * 256 + lane * 4;
  const ushort* base = encW + (size_t)(b * TE) * GG + g * HH + u4;
  float a0 = 0.f, a1 = 0.f, a2 = 0.f, a3 = 0.f;
#pragma unroll 8
  for (int tt = 0; tt < TE; ++tt) {
    ushort4 e4 = *(const ushort4*)(base + (size_t)tt * GG);
    const float wv = wt[tt];
    a0 += wv * bf2f(e4.x); a1 += wv * bf2f(e4.y);
    a2 += wv * bf2f(e4.z); a3 += wv * bf2f(e4.w);
  }
  float4 eg = *(const float4*)(embG + (size_t)(t * NB + b) * GG + g * HH + u4);
  float4 h0 = *(const float4*)(hWp + (size_t)b * WQN + HH + g * HH + u4);
  float4 h1 = *(const float4*)(hWp + (size_t)(NB * WQN) + (size_t)b * WQN + HH + g * HH + u4);
  gp[g][lane*4+0] = a0 * inv + eg.x + h0.x + h1.x;
  gp[g][lane*4+1] = a1 * inv + eg.y + h0.y + h1.y;
  gp[g][lane*4+2] = a2 * inv + eg.z + h0.z + h1.z;
  gp[g][lane*4+3] = a3 * inv + eg.w + h0.w + h1.w;
  __syncthreads();
  // LSTM pointwise: thread tid <-> local unit
  const float gi = gp[0][tid], gf = gp[1][tid], gg = gp[2][tid], go = gp[3][tid];
  const int idx = b * HH + hq * 256 + tid;
  const float c = c_cur[idx];
  const float cn = sigf(gf) * c + sigf(gi) * tanh_fast(gg);
  const float hn = sigf(go) * tanh_fast(cn);
  c_cur[idx] = cn;
  const ushort hb = f2bf(hn);
  h_bf[idx] = hb;
  hall[(size_t)t * (NB * HH) + idx] = hb;
}

// Row-wise in-place log-softmax over V (one block per output row)
__global__ __launch_bounds__(256) void k_logsoftmax(float* __restrict__ out) {
  const size_t row = blockIdx.x;
  float* p = out + row * VV;
  __shared__ float sm[256], ss[256];
  const int tid = threadIdx.x;
  float m = -1e30f, s = 0.f;
  for (int i = tid; i < VV; i += 256) {
    float x = p[i];
    float nm = fmaxf(m, x);
    s = s * __expf(m - nm) + __expf(x - nm);
    m = nm;
  }
  sm[tid] = m; ss[tid] = s;
  __syncthreads();
  for (int st = 128; st > 0; st >>= 1) {
    if (tid < st) {
      float m2 = fmaxf(sm[tid], sm[tid + st]);
      ss[tid] = ss[tid] * __expf(sm[tid] - m2) + ss[tid + st] * __expf(sm[tid + st] - m2);
      sm[tid] = m2;
    }
    __syncthreads();
  }
  float L = sm[0] + logf(ss[0]);
  __syncthreads();
  for (int i = tid; i < VV; i += 256) p[i] -= L;
}

extern "C" void kernel_launch(void* const* d_in, const int* in_sizes, int n_in,
                              void* d_out, int out_size, void* d_ws, size_t ws_size,
                              hipStream_t stream) {
  const float* enc   = (const float*)d_in[0];   // [32][128][1024]
  const float* ehid  = (const float*)d_in[1];   // [1][32][1024]
  const float* ecell = (const float*)d_in[2];
  const int*   tgt   = (const int*)d_in[3];     // [32][64]
  const float* etab  = (const float*)d_in[4];   // [32000][512]
  const float* Wa    = (const float*)d_in[5];   // [1024][1024]
  const float* Ua    = (const float*)d_in[6];
  const float* Va_w  = (const float*)d_in[7];   // [1][1024]
  // d_in[8] = Va_b: softmax-invariant constant, dropped
  const float* W_ih  = (const float*)d_in[9];   // [4096][1536]
  const float* W_hh  = (const float*)d_in[10];  // [4096][1024]
  const float* b_ih  = (const float*)d_in[11];
  const float* b_hh  = (const float*)d_in[12];
  const float* fc_w  = (const float*)d_in[13];  // [32000][1024]
  const float* fc_b  = (const float*)d_in[14];
  float* out = (float*)d_out;                   // [32][64][32000]
  float* ws = (float*)d_ws;

  // ---- workspace layout (float offsets), total 115.3 MB ----
  // U region [0, 16,777,216 fl): encW_bf + embG during compute; fcw_bf after recurrence
  ushort* encW_bf = (ushort*)ws;                    // [4096][4096] bf16 (32 MB)
  float*  embG    = ws + 8388608;                   // [2048][4096] f32  (32 MB)
  ushort* fcw_bf  = (ushort*)ws;                    // [32000][1024] bf16 (62.5 MB) AFTER recurrence
  ushort* Wqh_bf  = (ushort*)(ws + 16777216);       // [5120][1024] bf16
  ushort* encU_bf = (ushort*)(ws + 19398656);       // [4096][1024] bf16
  // enc_bf region reused for recurrence state after precompute GEMMs:
  ushort* enc_bf  = (ushort*)(ws + 21495808);       // [4096][1024] bf16 (precompute only)
  float*  hWp     = ws + 21495808;                  // [2][32][5120] f32 (overlaps enc_bf)
  float*  sc      = ws + 21823488;                  // [32][128]
  float*  c_cur   = ws + 21827584;                  // [32][1024]
  ushort* h_bf    = (ushort*)(ws + 21860352);       // [32][1024] bf16
  ushort* Wihc_bf = (ushort*)(ws + 23592960);       // [4096][1024] bf16
  ushort* Ua_bf   = (ushort*)(ws + 25690112);       // [1024][1024]
  ushort* emb_bf  = (ushort*)(ws + 26214400);       // [2048][512]
  ushort* WihE_bf = (ushort*)(ws + 26738688);       // [4096][512]
  ushort* hall_bf = (ushort*)(ws + 27787264);       // [64][32][1024] -> ends 28,835,840 fl

  // ---- precompute (uses enc_bf region before recurrence state overwrites it) ----
  k_emb<<<4096, 256, 0, stream>>>(tgt, etab, emb_bf);
  k_f2b<<<4096, 256, 0, stream>>>(enc, enc_bf, 1048576);
  k_f2b<<<1024, 256, 0, stream>>>(Ua, Ua_bf, 262144);
  k_f2b<<<1024, 256, 0, stream>>>(Wa, Wqh_bf, 262144);                      // rows 0..1023
  k_f2b<<<4096, 256, 0, stream>>>(W_hh, Wqh_bf + 1024 * HH, 1048576);       // rows 1024..5119
  k_f2b_s<<<4096, 256, 0, stream>>>(W_ih, 1536, 512, 256, Wihc_bf, 1048576);
  k_f2b_s<<<2048, 256, 0, stream>>>(W_ih, 1536, 0, 128, WihE_bf, 524288);
  // encU_bf = bf16(enc @ Ua^T): M=4096 N=1024 K=1024
  k_gemm_bf16<<<dim3(8, 32), 256, 0, stream>>>(enc_bf, HH, Ua_bf, HH, nullptr, nullptr,
                                               encU_bf, HH, HH, 0, 1);
  // encW_bf = bf16(enc @ W_ih[:,512:]^T): M=4096 N=4096 K=1024
  k_gemm_bf16<<<dim3(32, 32), 256, 0, stream>>>(enc_bf, HH, Wihc_bf, HH, nullptr, nullptr,
                                                encW_bf, GG, HH, 0, 1);
  // embG = emb @ W_ih[:,:512]^T + b_ih + b_hh: M=2048 N=4096 K=512 (f32 out)
  k_gemm_bf16<<<dim3(32, 16), 256, 0, stream>>>(emb_bf, EE, WihE_bf, EE, b_ih, b_hh,
                                                embG, GG, EE, 0, 0);
  // init recurrence state (AFTER gemms: h_bf/c_cur overlap enc_bf region)
  k_init<<<128, 256, 0, stream>>>(ehid, ecell, h_bf, c_cur);

  // ---- recurrence: 3 launches/step ----
  for (int t = 0; t < NT; ++t) {
    k_hw<<<dim3(40, 2), 256, 0, stream>>>(h_bf, Wqh_bf, hWp);
    k_scores<<<dim3(8, 32), 256, 0, stream>>>(hWp, encU_bf, Va_w, sc);
    k_ctxlstm<<<dim3(4, 32), 256, 0, stream>>>(sc, encW_bf, hWp, embG, c_cur,
                                               h_bf, hall_bf, t);
  }

  // ---- output projection + log-softmax ----
  k_f2b<<<32000, 256, 0, stream>>>(fc_w, fcw_bf, 8192000);
  k_gemm_bf16<<<dim3(250, 16), 256, 0, stream>>>(hall_bf, HH, fcw_bf, HH, fc_b, nullptr,
                                                 out, VV, HH, 1, 0);
  k_logsoftmax<<<2048, 256, 0, stream>>>(out);
}